// Round 1
// baseline (710.990 us; speedup 1.0000x reference)
//
#include <hip/hip_runtime.h>

typedef unsigned short u16;
typedef unsigned int u32;
using short8 = __attribute__((ext_vector_type(8))) short;
using f32x4  = __attribute__((ext_vector_type(4))) float;
using u32x4  = __attribute__((ext_vector_type(4))) u32;
using u16x4  = __attribute__((ext_vector_type(4))) u16;

#define N_CNT 50000
#define E_CNT 800000

__device__ __forceinline__ u16 f2bf(float f) {
  u32 u = __builtin_bit_cast(u32, f);
  u += 0x7fffu + ((u >> 16) & 1u);
  return (u16)(u >> 16);
}
__device__ __forceinline__ float siluf(float v) {
  return __fdividef(v, 1.f + __expf(-v));
}

// ---------------- prep: h -> bf16 ----------------
__global__ void k_hb(const float* __restrict__ h, u16* __restrict__ hb) {
  int i = (blockIdx.x * 256 + threadIdx.x) * 4;   // 6250*256*4 == 6,400,000 exact
  f32x4 v = *reinterpret_cast<const f32x4*>(h + i);
  u16x4 o = { f2bf(v[0]), f2bf(v[1]), f2bf(v[2]), f2bf(v[3]) };
  *reinterpret_cast<u16x4*>(hb + i) = o;
}

// ---------------- prep: weight fragments (MFMA B layout) ----------------
// frag element (tile t, kstep s, lane l, i): B[k=32s+8*(l>>4)+i][n=16t+(l&15)]
__global__ void k_wf(const float* __restrict__ w1, const float* __restrict__ w2,
                     const float* __restrict__ wc1, const float* __restrict__ wn1,
                     const float* __restrict__ wn2,
                     u16* __restrict__ wef, u16* __restrict__ wnf) {
  int idx = blockIdx.x * 256 + threadIdx.x;     // 464*256 == 118784 exact
  if (idx < 36864) {                            // w1f: 8t x 9s, K=288 (>=273 zero-pad)
    int i = idx & 7, l = (idx >> 3) & 63, rest = idx >> 9;
    int s = rest % 9, t = rest / 9;
    int k = 32 * s + 8 * (l >> 4) + i, n = 16 * t + (l & 15);
    wef[idx] = (k < 273) ? f2bf(w1[k * 128 + n]) : (u16)0;
  } else if (idx < 53248) {                     // w2f: 8t x 4s
    int u = idx - 36864;
    int i = u & 7, l = (u >> 3) & 63, rest = u >> 9;
    int s = rest & 3, t = rest >> 2;
    int k = 32 * s + 8 * (l >> 4) + i, n = 16 * t + (l & 15);
    wef[idx] = f2bf(w2[k * 128 + n]);
  } else if (idx < 69632) {                     // wc1f: 8t x 4s
    int u = idx - 53248;
    int i = u & 7, l = (u >> 3) & 63, rest = u >> 9;
    int s = rest & 3, t = rest >> 2;
    int k = 32 * s + 8 * (l >> 4) + i, n = 16 * t + (l & 15);
    wef[idx] = f2bf(wc1[k * 128 + n]);
  } else if (idx < 102400) {                    // wn1f: 8t x 8s (K=256)
    int u = idx - 69632;
    int i = u & 7, l = (u >> 3) & 63, rest = u >> 9;
    int s = rest & 7, t = rest >> 3;
    int k = 32 * s + 8 * (l >> 4) + i, n = 16 * t + (l & 15);
    wnf[u] = f2bf(wn1[k * 128 + n]);
  } else if (idx < 118784) {                    // wn2f: 8t x 4s
    int u = idx - 102400;
    int i = u & 7, l = (u >> 3) & 63, rest = u >> 9;
    int s = rest & 3, t = rest >> 2;
    int k = 32 * s + 8 * (l >> 4) + i, n = 16 * t + (l & 15);
    wnf[32768 + u] = f2bf(wn2[k * 128 + n]);
  }
}

// ---------------- edge kernel ----------------
// LDS: w1f 73728 | w2f 32768 | wc1f 32768 | per-wave 5888:
//   atail[16][32]u16 @0, mbuf[16][136]u16 @1024, cd[16][4]f32 @5376,
//   rcl[16][2]int @5632, dsqb[16]f32 @5760
__global__ __launch_bounds__(256, 1)
void egnn_edge(const u16* __restrict__ hb, const float* __restrict__ xc,
               const float* __restrict__ ea, const int* __restrict__ eidx,
               const u16* __restrict__ wef,
               const float* __restrict__ b1v, const float* __restrict__ b2v,
               const float* __restrict__ bc1v, const float* __restrict__ wc2v,
               float* __restrict__ m_i, float* __restrict__ x_acc) {
  extern __shared__ char smem[];
  const int tid = threadIdx.x;
  {
    const u32x4* src = reinterpret_cast<const u32x4*>(wef);
    u32x4* dst = reinterpret_cast<u32x4*>(smem);
    for (int i = tid; i < 8704; i += 256) dst[i] = src[i];
  }
  __syncthreads();
  const int w = tid >> 6, lane = tid & 63;
  const int g = lane >> 4, c15 = lane & 15;
  char* wb = smem + 139264 + w * 5888;
  u16* atail  = (u16*)wb;
  u16* mbuf   = (u16*)(wb + 1024);
  float* cd   = (float*)(wb + 5376);
  int* rcl    = (int*)(wb + 5632);
  float* dsqb = (float*)(wb + 5760);
  const u16* w1f  = (const u16*)smem;
  const u16* w2f  = (const u16*)(smem + 73728);
  const u16* wc1f = (const u16*)(smem + 106496);

  float b1r[8], b2r[8], bc1r[8], wc2r[8];
#pragma unroll
  for (int t = 0; t < 8; ++t) {
    b1r[t]  = b1v[t * 16 + c15];
    b2r[t]  = b2v[t * 16 + c15];
    bc1r[t] = bc1v[t * 16 + c15];
    wc2r[t] = wc2v[t * 16 + c15];
  }

  for (int tile = blockIdx.x; tile < E_CNT / 64; tile += gridDim.x) {
    const int ebase = tile * 64 + w * 16;
    // phase A: per-edge geometry (lanes 0..15)
    if (lane < 16) {
      int gi = ebase + lane;
      int r = eidx[gi], c = eidx[E_CNT + gi];
      float d0 = xc[3 * r + 0] - xc[3 * c + 0];
      float d1 = xc[3 * r + 1] - xc[3 * c + 1];
      float d2 = xc[3 * r + 2] - xc[3 * c + 2];
      float dsq = d0 * d0 + d1 * d1 + d2 * d2;
      cd[lane * 4 + 0] = d0; cd[lane * 4 + 1] = d1; cd[lane * 4 + 2] = d2;
      cd[lane * 4 + 3] = rsqrtf(dsq + 1e-8f);
      dsqb[lane] = dsq;
      rcl[lane * 2 + 0] = r; rcl[lane * 2 + 1] = c;
    }
    // phase B: tail A-tile (k=256..287): [dist_sq, ea0..ea15, 0...]
    {
      int e = lane >> 2, kk = (lane & 3) * 8;
      int gi = ebase + e;
      float dq = dsqb[e];
      short8 v;
#pragma unroll
      for (int j = 0; j < 8; ++j) {
        int kc = kk + j;
        float f = 0.f;
        if (kc == 0) f = dq;
        else if (kc <= 16) f = ea[gi * 16 + (kc - 1)];
        v[j] = (short)f2bf(f);
      }
      *reinterpret_cast<short8*>(atail + e * 32 + kk) = v;
    }
    // layer 1: einput[16,288] @ we_w1
    int re = rcl[c15 * 2 + 0], ce = rcl[c15 * 2 + 1];
    short8 af[9];
#pragma unroll
    for (int s = 0; s < 4; ++s)
      af[s] = *reinterpret_cast<const short8*>(hb + re * 128 + s * 32 + g * 8);
#pragma unroll
    for (int s = 0; s < 4; ++s)
      af[4 + s] = *reinterpret_cast<const short8*>(hb + ce * 128 + s * 32 + g * 8);
    af[8] = *reinterpret_cast<const short8*>(atail + c15 * 32 + g * 8);

    f32x4 acc[8];
#pragma unroll
    for (int t = 0; t < 8; ++t) acc[t] = (f32x4){0.f, 0.f, 0.f, 0.f};
#pragma unroll
    for (int s = 0; s < 9; ++s) {
#pragma unroll
      for (int t = 0; t < 8; ++t) {
        short8 bf = *reinterpret_cast<const short8*>(w1f + ((t * 9 + s) * 64 + lane) * 8);
        acc[t] = __builtin_amdgcn_mfma_f32_16x16x32_bf16(af[s], bf, acc[t], 0, 0, 0);
      }
    }
#pragma unroll
    for (int t = 0; t < 8; ++t)
#pragma unroll
      for (int i = 0; i < 4; ++i) {
        float v = siluf(acc[t][i] + b1r[t]);
        mbuf[(g * 4 + i) * 136 + t * 16 + c15] = f2bf(v);
      }
    // layer 2: m1 @ we_w2
    short8 a2[4];
#pragma unroll
    for (int s = 0; s < 4; ++s)
      a2[s] = *reinterpret_cast<const short8*>(mbuf + c15 * 136 + s * 32 + g * 8);
    f32x4 acc2[8];
#pragma unroll
    for (int t = 0; t < 8; ++t) acc2[t] = (f32x4){0.f, 0.f, 0.f, 0.f};
#pragma unroll
    for (int s = 0; s < 4; ++s) {
#pragma unroll
      for (int t = 0; t < 8; ++t) {
        short8 bf = *reinterpret_cast<const short8*>(w2f + ((t * 4 + s) * 64 + lane) * 8);
        acc2[t] = __builtin_amdgcn_mfma_f32_16x16x32_bf16(a2[s], bf, acc2[t], 0, 0, 0);
      }
    }
    int rows4[4];
#pragma unroll
    for (int i = 0; i < 4; ++i) rows4[i] = rcl[(g * 4 + i) * 2];
#pragma unroll
    for (int t = 0; t < 8; ++t)
#pragma unroll
      for (int i = 0; i < 4; ++i) {
        float v = siluf(acc2[t][i] + b2r[t]);
        atomicAdd(&m_i[rows4[i] * 128 + t * 16 + c15], v);
        mbuf[(g * 4 + i) * 136 + t * 16 + c15] = f2bf(v);
      }
    // coord MLP: silu(m2 @ wc1 + bc1) . wc2 -> tanh
    short8 a3[4];
#pragma unroll
    for (int s = 0; s < 4; ++s)
      a3[s] = *reinterpret_cast<const short8*>(mbuf + c15 * 136 + s * 32 + g * 8);
    f32x4 acc3[8];
#pragma unroll
    for (int t = 0; t < 8; ++t) acc3[t] = (f32x4){0.f, 0.f, 0.f, 0.f};
#pragma unroll
    for (int s = 0; s < 4; ++s) {
#pragma unroll
      for (int t = 0; t < 8; ++t) {
        short8 bf = *reinterpret_cast<const short8*>(wc1f + ((t * 4 + s) * 64 + lane) * 8);
        acc3[t] = __builtin_amdgcn_mfma_f32_16x16x32_bf16(a3[s], bf, acc3[t], 0, 0, 0);
      }
    }
    float p[4] = {0.f, 0.f, 0.f, 0.f};
#pragma unroll
    for (int t = 0; t < 8; ++t)
#pragma unroll
      for (int i = 0; i < 4; ++i)
        p[i] += siluf(acc3[t][i] + bc1r[t]) * wc2r[t];
#pragma unroll
    for (int m = 1; m <= 8; m <<= 1) {
#pragma unroll
      for (int i = 0; i < 4; ++i) p[i] += __shfl_xor(p[i], m, 64);
    }
    if (c15 == 0) {
#pragma unroll
      for (int i = 0; i < 4; ++i) {
        int e = g * 4 + i;
        float fac = cd[e * 4 + 3] * tanhf(p[i]);
        int r = rcl[e * 2];
        atomicAdd(&x_acc[r * 4 + 0], cd[e * 4 + 0] * fac);
        atomicAdd(&x_acc[r * 4 + 1], cd[e * 4 + 1] * fac);
        atomicAdd(&x_acc[r * 4 + 2], cd[e * 4 + 2] * fac);
        atomicAdd(&x_acc[r * 4 + 3], 1.0f);
      }
    }
  }
}

// ---------------- node kernel ----------------
// LDS: wn1f 65536 | wn2f 32768 | per-wave mbuf[16][136]u16 (4352)
__global__ __launch_bounds__(256, 1)
void egnn_node(const u16* __restrict__ hb, const float* __restrict__ h,
               const float* __restrict__ m_i, const u16* __restrict__ wnf,
               const float* __restrict__ bn1, const float* __restrict__ bn2,
               const float* __restrict__ lng, const float* __restrict__ lnb,
               float* __restrict__ h_out) {
  extern __shared__ char smem[];
  const int tid = threadIdx.x;
  {
    const u32x4* src = reinterpret_cast<const u32x4*>(wnf);
    u32x4* dst = reinterpret_cast<u32x4*>(smem);
    for (int i = tid; i < 6144; i += 256) dst[i] = src[i];
  }
  __syncthreads();
  const int w = tid >> 6, lane = tid & 63;
  const int g = lane >> 4, c15 = lane & 15;
  const u16* wn1f = (const u16*)smem;
  const u16* wn2f = (const u16*)(smem + 65536);
  u16* mbuf = (u16*)(smem + 98304 + w * 4352);

  float bn1r[8], bn2r[8], lngr[8], lnbr[8];
#pragma unroll
  for (int t = 0; t < 8; ++t) {
    bn1r[t] = bn1[t * 16 + c15];
    bn2r[t] = bn2[t * 16 + c15];
    lngr[t] = lng[t * 16 + c15];
    lnbr[t] = lnb[t * 16 + c15];
  }

  for (int nt = blockIdx.x; nt < 782; nt += gridDim.x) {
    int nbase = nt * 64 + w * 16;
    if (nbase >= N_CNT) continue;   // tail: 50000 = 781*64 + 16, wave-aligned
    int nr = nbase + c15;
    short8 af[8];
#pragma unroll
    for (int s = 0; s < 4; ++s)
      af[s] = *reinterpret_cast<const short8*>(hb + nr * 128 + s * 32 + g * 8);
#pragma unroll
    for (int s = 0; s < 4; ++s) {
      f32x4 v0 = *reinterpret_cast<const f32x4*>(m_i + nr * 128 + s * 32 + g * 8);
      f32x4 v1 = *reinterpret_cast<const f32x4*>(m_i + nr * 128 + s * 32 + g * 8 + 4);
      short8 t8;
#pragma unroll
      for (int j = 0; j < 4; ++j) t8[j] = (short)f2bf(v0[j]);
#pragma unroll
      for (int j = 0; j < 4; ++j) t8[4 + j] = (short)f2bf(v1[j]);
      af[4 + s] = t8;
    }
    f32x4 acc[8];
#pragma unroll
    for (int t = 0; t < 8; ++t) acc[t] = (f32x4){0.f, 0.f, 0.f, 0.f};
#pragma unroll
    for (int s = 0; s < 8; ++s) {
#pragma unroll
      for (int t = 0; t < 8; ++t) {
        short8 bf = *reinterpret_cast<const short8*>(wn1f + ((t * 8 + s) * 64 + lane) * 8);
        acc[t] = __builtin_amdgcn_mfma_f32_16x16x32_bf16(af[s], bf, acc[t], 0, 0, 0);
      }
    }
#pragma unroll
    for (int t = 0; t < 8; ++t)
#pragma unroll
      for (int i = 0; i < 4; ++i) {
        float v = siluf(acc[t][i] + bn1r[t]);
        mbuf[(g * 4 + i) * 136 + t * 16 + c15] = f2bf(v);
      }
    short8 a2[4];
#pragma unroll
    for (int s = 0; s < 4; ++s)
      a2[s] = *reinterpret_cast<const short8*>(mbuf + c15 * 136 + s * 32 + g * 8);
    f32x4 acc2[8];
#pragma unroll
    for (int t = 0; t < 8; ++t) acc2[t] = (f32x4){0.f, 0.f, 0.f, 0.f};
#pragma unroll
    for (int s = 0; s < 4; ++s) {
#pragma unroll
      for (int t = 0; t < 8; ++t) {
        short8 bf = *reinterpret_cast<const short8*>(wn2f + ((t * 4 + s) * 64 + lane) * 8);
        acc2[t] = __builtin_amdgcn_mfma_f32_16x16x32_bf16(a2[s], bf, acc2[t], 0, 0, 0);
      }
    }
    // residual + layernorm
    float vres[8][4];
    float s1[4] = {0.f, 0.f, 0.f, 0.f}, s2[4] = {0.f, 0.f, 0.f, 0.f};
#pragma unroll
    for (int t = 0; t < 8; ++t)
#pragma unroll
      for (int i = 0; i < 4; ++i) {
        int n = nbase + g * 4 + i;
        float v = acc2[t][i] + bn2r[t] + h[n * 128 + t * 16 + c15];
        vres[t][i] = v; s1[i] += v; s2[i] += v * v;
      }
#pragma unroll
    for (int m = 1; m <= 8; m <<= 1) {
#pragma unroll
      for (int i = 0; i < 4; ++i) {
        s1[i] += __shfl_xor(s1[i], m, 64);
        s2[i] += __shfl_xor(s2[i], m, 64);
      }
    }
    float mu[4], rstd[4];
#pragma unroll
    for (int i = 0; i < 4; ++i) {
      mu[i] = s1[i] * (1.0f / 128.0f);
      float var = s2[i] * (1.0f / 128.0f) - mu[i] * mu[i];
      rstd[i] = rsqrtf(var + 1e-5f);
    }
#pragma unroll
    for (int t = 0; t < 8; ++t)
#pragma unroll
      for (int i = 0; i < 4; ++i) {
        int n = nbase + g * 4 + i;
        if (n < N_CNT)
          h_out[n * 128 + t * 16 + c15] =
              (vres[t][i] - mu[i]) * rstd[i] * lngr[t] + lnbr[t];
      }
  }
}

// ---------------- x_out ----------------
__global__ void egnn_xout(const float* __restrict__ x, const float* __restrict__ x_acc,
                          float* __restrict__ xo) {
  int n = blockIdx.x * 256 + threadIdx.x;
  if (n < N_CNT) {
    float deg = fmaxf(x_acc[n * 4 + 3], 1.0f);
    xo[n * 3 + 0] = x[n * 3 + 0] + x_acc[n * 4 + 0] / deg;
    xo[n * 3 + 1] = x[n * 3 + 1] + x_acc[n * 4 + 1] / deg;
    xo[n * 3 + 2] = x[n * 3 + 2] + x_acc[n * 4 + 2] / deg;
  }
}

extern "C" void kernel_launch(void* const* d_in, const int* in_sizes, int n_in,
                              void* d_out, int out_size, void* d_ws, size_t ws_size,
                              hipStream_t stream) {
  const float* h     = (const float*)d_in[0];
  const float* x     = (const float*)d_in[1];
  const float* ea    = (const float*)d_in[2];
  const float* we_w1 = (const float*)d_in[3];
  const float* we_b1 = (const float*)d_in[4];
  const float* we_w2 = (const float*)d_in[5];
  const float* we_b2 = (const float*)d_in[6];
  const float* wc_w1 = (const float*)d_in[7];
  const float* wc_b1 = (const float*)d_in[8];
  const float* wc_w2 = (const float*)d_in[9];
  const float* wn_w1 = (const float*)d_in[10];
  const float* wn_b1 = (const float*)d_in[11];
  const float* wn_w2 = (const float*)d_in[12];
  const float* wn_b2 = (const float*)d_in[13];
  const float* ln_g  = (const float*)d_in[14];
  const float* ln_b  = (const float*)d_in[15];
  const int* eidx    = (const int*)d_in[16];
  float* out = (float*)d_out;
  char* ws = (char*)d_ws;

  u16* hb     = (u16*)(ws);                      // 12,800,000 B
  float* m_i  = (float*)(ws + 12800000);         // 25,600,000 B
  float* xacc = (float*)(ws + 38400000);         //    800,000 B
  u16* wef    = (u16*)(ws + 39200000);           //    139,264 B
  u16* wnf    = (u16*)(ws + 39339264);           //     98,304 B

  hipMemsetAsync(m_i, 0, 26400000, stream);      // m_i + x_acc
  k_hb<<<6250, 256, 0, stream>>>(h, hb);
  k_wf<<<464, 256, 0, stream>>>(we_w1, we_w2, wc_w1, wn_w1, wn_w2, wef, wnf);

  hipFuncSetAttribute(reinterpret_cast<const void*>(egnn_edge),
                      hipFuncAttributeMaxDynamicSharedMemorySize, 162816);
  hipFuncSetAttribute(reinterpret_cast<const void*>(egnn_node),
                      hipFuncAttributeMaxDynamicSharedMemorySize, 115712);

  egnn_edge<<<512, 256, 162816, stream>>>(hb, x, ea, eidx, wef,
                                          we_b1, we_b2, wc_b1, wc_w2, m_i, xacc);
  egnn_node<<<256, 256, 115712, stream>>>(hb, h, m_i, wnf,
                                          wn_b1, wn_b2, ln_g, ln_b, out);
  egnn_xout<<<196, 256, 0, stream>>>(x, xacc, out + 6400000);
}